// Round 1
// baseline (3845.273 us; speedup 1.0000x reference)
//
#include <hip/hip_runtime.h>
#include <stdint.h>
#include <stddef.h>

// LSTM_63488206569533: B=128, T=1024, I=256, H=512, fp32 in/out.
// Persistent kernel: 256 WGs (8 batch-groups x 32 unit-slices), one per CU.
// R3: tagged-dataflow h exchange. Each h value is stored as a 32-bit word
//     (tag<<16 | bf16), double-buffered [2][B][H]. Consumers poll the DATA
//     (16 coalesced u64 agent loads/thread), so the h transfer overlaps the
//     synchronization. No counters, no store-ack fence, no separate h load.
//     2 barriers/step (was 4); x(t+1) prefetched + staged under h-MFMAs.

#define Bn   128
#define Tn   1024
#define In   256
#define Hn   512
#define PM   8     // batch groups
#define PN   32    // unit slices
#define BPW  16    // batches per WG
#define UPW  16    // units per WG
#define APAD 776   // padded A row length in bf16 elems (1552 B, 16B-aligned rows)
#define GPAD 17    // gate_lds padded row stride (kills 4-way write conflict)

typedef float f4 __attribute__((ext_vector_type(4)));
typedef short s8 __attribute__((ext_vector_type(8)));
typedef unsigned long long u64;

static __device__ __forceinline__ short f2bf(float f) {
  union { float f; unsigned u; } v; v.f = f;
  unsigned u = v.u;
  return (short)((u + 0x7FFFu + ((u >> 16) & 1u)) >> 16);  // RNE
}

__global__ __launch_bounds__(256, 1)
void lstm_persist(const float* __restrict__ x,
                  const float* __restrict__ W_ih,
                  const float* __restrict__ W_hh,
                  const float* __restrict__ b_ih,
                  const float* __restrict__ b_hh,
                  const float* __restrict__ fc_w,
                  const float* __restrict__ fc_b,
                  float* __restrict__ out,
                  unsigned* __restrict__ hw)   // [2][Bn][Hn] tagged dwords
{
  const int tid  = threadIdx.x;
  const int wave = tid >> 6;    // 0..3  == gate type (i,f,g,o)
  const int lane = tid & 63;
  const int n16  = lane & 15;   // MFMA: batch row (A) / gate col (B)
  const int q    = lane >> 4;   // MFMA quad -> k-subblock
  const int bg   = blockIdx.x & 7;   // batch group
  const int ns   = blockIdx.x >> 3;  // unit slice 0..31

  __shared__ short A_lds[16 * APAD];       // [batch 16][k 768(+pad)] bf16
  __shared__ float gate_lds[4 * 16 * GPAD];

  // ---- one-time: preload this wave's 16 W rows into B-fragments (bf16) ----
  s8 bfrag[24];
  {
    const int grow = wave * Hn + ns * UPW + n16;  // global gate row in [0,4H)
#pragma unroll
    for (int kk = 0; kk < 24; ++kk) {
      const float* p = (kk < 8)
        ? (W_ih + (size_t)grow * In + kk * 32 + q * 8)
        : (W_hh + (size_t)grow * Hn + (kk - 8) * 32 + q * 8);
      f4 lo = ((const f4*)p)[0];
      f4 hi = ((const f4*)p)[1];
      s8 b;
      b[0]=f2bf(lo[0]); b[1]=f2bf(lo[1]); b[2]=f2bf(lo[2]); b[3]=f2bf(lo[3]);
      b[4]=f2bf(hi[0]); b[5]=f2bf(hi[1]); b[6]=f2bf(hi[2]); b[7]=f2bf(hi[3]);
      bfrag[kk] = b;
    }
  }

  // ---- elementwise-phase mapping: tid -> (batch em, unit en) ----
  const int em  = tid >> 4;
  const int en  = tid & 15;
  const int ug  = ns * UPW + en;     // global unit
  const int bgl = bg * BPW + em;     // global batch
  const float bia = b_ih[ug]        + b_hh[ug];
  const float bfa = b_ih[Hn + ug]   + b_hh[Hn + ug];
  const float bga = b_ih[2*Hn + ug] + b_hh[2*Hn + ug];
  const float boa = b_ih[3*Hn + ug] + b_hh[3*Hn + ug];

  const float* xbase = x + (size_t)bgl * Tn * In + en * 16;
  const short* aptr  = A_lds + n16 * APAD + q * 8;
  const u64*   hw64  = (const u64*)hw;

  // ---- prologue: stage x(0) ----
  {
    const f4* xp = (const f4*)xbase;
    f4 a = xp[0], b = xp[1], c = xp[2], d = xp[3];
    s8 lo, hi;
    lo[0]=f2bf(a[0]); lo[1]=f2bf(a[1]); lo[2]=f2bf(a[2]); lo[3]=f2bf(a[3]);
    lo[4]=f2bf(b[0]); lo[5]=f2bf(b[1]); lo[6]=f2bf(b[2]); lo[7]=f2bf(b[3]);
    hi[0]=f2bf(c[0]); hi[1]=f2bf(c[1]); hi[2]=f2bf(c[2]); hi[3]=f2bf(c[3]);
    hi[4]=f2bf(d[0]); hi[5]=f2bf(d[1]); hi[6]=f2bf(d[2]); hi[7]=f2bf(d[3]);
    s8* dst = (s8*)(A_lds + em * APAD + en * 16);
    dst[0] = lo; dst[1] = hi;
  }

  float creg = 0.f, hreg = 0.f;
  __syncthreads();

  for (int t = 0; t < Tn; ++t) {
    // (1) issue poll loads FIRST: thread tid owns u64 index j*256+tid of this
    //     group's [16 batch][512 unit] dword block -> per-instruction access
    //     is a contiguous 512B wave load. u64 j covers batch j, units 2tid,2tid+1.
    u64 vals[16];
    const u64* pb = hw64 + ((t & 1) ? (Bn * Hn / 2) : 0) + bg * (BPW * Hn / 2) + tid;
    if (t > 0) {
#pragma unroll
      for (int j = 0; j < 16; ++j)
        vals[j] = __hip_atomic_load(pb + j * 256, __ATOMIC_RELAXED, __HIP_MEMORY_SCOPE_AGENT);
    }

    // (2) prefetch x(t+1) into registers (consumed after barrier A)
    const int tn = (t + 1 < Tn) ? (t + 1) : t;
    const f4* xp = (const f4*)(xbase + (size_t)tn * In);
    f4 xa = xp[0], xb = xp[1], xc = xp[2], xd = xp[3];

    // (3) x-part MFMAs from A_lds while poll loads are in flight
    f4 acc = {0.f, 0.f, 0.f, 0.f};
#pragma unroll
    for (int kk = 0; kk < 8; ++kk) {
      s8 a = *(const s8*)(aptr + kk * 32);
      acc = __builtin_amdgcn_mfma_f32_16x16x32_bf16(a, bfrag[kk], acc, 0, 0, 0);
    }

    if (t > 0) {
      // (4) tag check; retry is self-throttled at load RTT, no sleep needed.
      //     Words are stable once tagged t (overwrite with t+2 requires every
      //     WG of this group to have finished this very poll -> no race).
      const unsigned tt = (unsigned)t;
      const u64 WANT = ((u64)tt << 16) | ((u64)tt << 48);
      const u64 MASK = 0xFFFF0000FFFF0000ull;
      for (;;) {
        u64 bad = 0;
#pragma unroll
        for (int j = 0; j < 16; ++j) bad |= (vals[j] ^ WANT) & MASK;
        if (bad == 0) break;
#pragma unroll
        for (int j = 0; j < 16; ++j)
          vals[j] = __hip_atomic_load(pb + j * 256, __ATOMIC_RELAXED, __HIP_MEMORY_SCOPE_AGENT);
      }
      // (5) stage h -> A_lds[batch j][256 + 2tid .. +1]: one b32 per batch,
      //     dword addr = j*388 + 128 + tid -> conflict-free (2-way).
#pragma unroll
      for (int j = 0; j < 16; ++j) {
        unsigned w = (unsigned)(vals[j] & 0xFFFFu) | ((unsigned)(vals[j] >> 32) << 16);
        *(unsigned*)(A_lds + j * APAD + 256 + 2 * tid) = w;
      }
    }
    __syncthreads();   // (A) h staged; all x(t) LDS reads complete

    if (t > 0) {
      // (6) h-part MFMAs
#pragma unroll
      for (int kk = 8; kk < 24; ++kk) {
        s8 a = *(const s8*)(aptr + kk * 32);
        acc = __builtin_amdgcn_mfma_f32_16x16x32_bf16(a, bfrag[kk], acc, 0, 0, 0);
      }
    }

    // (7) stage x(t+1) -> A_lds (reads of x(t) finished before barrier A)
    {
      s8 lo, hi;
      lo[0]=f2bf(xa[0]); lo[1]=f2bf(xa[1]); lo[2]=f2bf(xa[2]); lo[3]=f2bf(xa[3]);
      lo[4]=f2bf(xb[0]); lo[5]=f2bf(xb[1]); lo[6]=f2bf(xb[2]); lo[7]=f2bf(xb[3]);
      hi[0]=f2bf(xc[0]); hi[1]=f2bf(xc[1]); hi[2]=f2bf(xc[2]); hi[3]=f2bf(xc[3]);
      hi[4]=f2bf(xd[0]); hi[5]=f2bf(xd[1]); hi[6]=f2bf(xd[2]); hi[7]=f2bf(xd[3]);
      s8* dst = (s8*)(A_lds + em * APAD + en * 16);
      dst[0] = lo; dst[1] = hi;
    }

    // (8) exchange gates through LDS (C-layout: row=(q*4+r)=batch, col=n16=unit)
#pragma unroll
    for (int r = 0; r < 4; ++r)
      gate_lds[wave * (16 * GPAD) + (q * 4 + r) * GPAD + n16] = acc[r];
    __syncthreads();   // (B) gates ready; x(t+1) staged

    // (9) per-(batch,unit) LSTM cell update; c stays in a register
    {
      float zi = gate_lds[0 * (16 * GPAD) + em * GPAD + en] + bia;
      float zf = gate_lds[1 * (16 * GPAD) + em * GPAD + en] + bfa;
      float zg = gate_lds[2 * (16 * GPAD) + em * GPAD + en] + bga;
      float zo = gate_lds[3 * (16 * GPAD) + em * GPAD + en] + boa;
      float gi = 1.f / (1.f + __expf(-zi));
      float gf = 1.f / (1.f + __expf(-zf));
      float gg = 2.f / (1.f + __expf(-2.f * zg)) - 1.f;   // tanh
      float go = 1.f / (1.f + __expf(-zo));
      creg = gf * creg + gi * gg;
      float tc = 2.f / (1.f + __expf(-2.f * creg)) - 1.f; // tanh(c)
      hreg = go * tc;
      // fire-and-forget tagged store: (t+1)<<16 | bf16(h); no ack, no fence.
      unsigned word = ((unsigned)(t + 1) << 16) | (unsigned)(unsigned short)f2bf(hreg);
      unsigned* hp = hw + (((t + 1) & 1) ? (Bn * Hn) : 0) + bgl * Hn + ug;
      __hip_atomic_store(hp, word, __ATOMIC_RELAXED, __HIP_MEMORY_SCOPE_AGENT);
    }
    // no trailing barrier: next iteration's LDS writes are fenced by (A)/(B)
  }

  // ---- epilogue: out[b] = sum_u hT[b,u] * fc_w[u] + fc_b ----
  float partial = hreg * fc_w[ug];
#pragma unroll
  for (int off = 1; off < 16; off <<= 1)
    partial += __shfl_xor(partial, off, 64);   // reduce over the 16 units
  if (en == 0) {
    if (ns == 0) partial += fc_b[0];           // fc_b exactly once per batch
    atomicAdd(&out[bgl], partial);
  }
}

extern "C" void kernel_launch(void* const* d_in, const int* in_sizes, int n_in,
                              void* d_out, int out_size, void* d_ws, size_t ws_size,
                              hipStream_t stream) {
  const float* x    = (const float*)d_in[0];
  const float* W_ih = (const float*)d_in[1];
  const float* W_hh = (const float*)d_in[2];
  const float* b_ih = (const float*)d_in[3];
  const float* b_hh = (const float*)d_in[4];
  const float* fc_w = (const float*)d_in[5];
  const float* fc_b = (const float*)d_in[6];
  float* out = (float*)d_out;

  unsigned* hw = (unsigned*)d_ws;   // [2][Bn][Hn] tagged dwords = 512 KB

  // zero tags every launch (stale tags from a previous run would alias t)
  hipMemsetAsync(d_ws, 0, (size_t)2 * Bn * Hn * sizeof(unsigned), stream);
  hipMemsetAsync(d_out, 0, Bn * sizeof(float), stream);  // out via atomics

  lstm_persist<<<dim3(PM * PN), dim3(256), 0, stream>>>(
      x, W_ih, W_hh, b_ih, b_hh, fc_w, fc_b, out, hw);
}